// Round 1
// baseline (208.623 us; speedup 1.0000x reference)
//
#include <hip/hip_runtime.h>
#include <hip/hip_bf16.h>
#include <math.h>

#define N_NODES 50000
#define N_EDGES 800000
#define N_FEAT 128
#define HIDDEN 16
#define N_CLASSES 16

// ---------------------------------------------------------------------------
// K1: per-node transform for layer 1.
// Computes h0 = x@w1[0], h1 = x@w1[1], p1 = x@root1 + b1.
// h0/h1 written interleaved into AB[N][32] (cols 0..15 = h0, 16..31 = h1)
// so the edge kernel gathers one contiguous 128B block per edge.
// 16 threads per node (one per output column), weights staged in LDS
// transposed [48][132] (pad 132 -> <=2-way bank conflicts on float4 reads).
// ---------------------------------------------------------------------------
__global__ __launch_bounds__(256) void k_node1(
    const float* __restrict__ x, const float* __restrict__ w1,
    const float* __restrict__ root1, const float* __restrict__ b1,
    float* __restrict__ AB, float* __restrict__ C)
{
    __shared__ float W[48 * 132];
    for (int t = threadIdx.x; t < 48 * 128; t += 256) {
        int o = t >> 7;        // 0..47
        int i = t & 127;       // 0..127
        float v;
        if (o < 16)       v = w1[i * 16 + o];
        else if (o < 32)  v = w1[2048 + i * 16 + (o - 16)];
        else              v = root1[i * 16 + (o - 32)];
        W[o * 132 + i] = v;
    }
    __syncthreads();

    int nl = threadIdx.x >> 4;          // 0..15 node within block
    int o  = threadIdx.x & 15;          // output column
    int n  = blockIdx.x * 16 + nl;      // grid sized exactly: 3125*16 = 50000

    const float4* xr = (const float4*)(x + (size_t)n * N_FEAT);
    float a0 = 0.f, a1 = 0.f, ar = 0.f;
#pragma unroll
    for (int i4 = 0; i4 < 32; ++i4) {
        float4 xv = xr[i4];
        float4 wa = *(const float4*)&W[o * 132 + 4 * i4];
        float4 wb = *(const float4*)&W[(o + 16) * 132 + 4 * i4];
        float4 wr = *(const float4*)&W[(o + 32) * 132 + 4 * i4];
        a0 += xv.x * wa.x + xv.y * wa.y + xv.z * wa.z + xv.w * wa.w;
        a1 += xv.x * wb.x + xv.y * wb.y + xv.z * wb.z + xv.w * wb.w;
        ar += xv.x * wr.x + xv.y * wr.y + xv.z * wr.z + xv.w * wr.w;
    }
    AB[(size_t)n * 32 + o]      = a0;
    AB[(size_t)n * 32 + 16 + o] = a1;
    C[(size_t)n * 16 + o]       = ar + b1[o];
}

// ---------------------------------------------------------------------------
// K2/K4: edge scatter. 16 lanes per edge, lane o handles feature o.
// msg = (1-u)*h0[src][o] + u*h1[src][o]; atomicAdd into agg[dst][o].
// Pass 1 also accumulates degree (lane 0).
// ---------------------------------------------------------------------------
template <bool ADD_DEG>
__global__ __launch_bounds__(256) void k_edge(
    const int* __restrict__ src, const int* __restrict__ dst,
    const float* __restrict__ u, const float* __restrict__ AB,
    float* __restrict__ agg, float* __restrict__ deg)
{
    int t = blockIdx.x * 256 + threadIdx.x;   // exact: 50000 blocks * 256
    int e = t >> 4;
    int o = t & 15;
    int s = src[e];
    int d = dst[e];
    float uv = u[e];
    float m = (1.0f - uv) * AB[(size_t)s * 32 + o] + uv * AB[(size_t)s * 32 + 16 + o];
    atomicAdd(&agg[(size_t)d * 16 + o], m);
    if (ADD_DEG && o == 0) atomicAdd(&deg[d], 1.0f);
}

// ---------------------------------------------------------------------------
// K3: finish layer 1 (mean + root + bias + ELU) and apply layer-2 node
// transform (h@w2[0], h@w2[1], h@root2 + b2). 16 threads per node; h row
// exchanged via LDS ([16][17] pad).
// In-place: C (p1 in) becomes p2 out; AB overwritten with layer-2 h0/h1.
// ---------------------------------------------------------------------------
__global__ __launch_bounds__(256) void k_node2(
    const float* __restrict__ agg, const float* __restrict__ deg,
    float* __restrict__ C, const float* __restrict__ w2,
    const float* __restrict__ root2, const float* __restrict__ b2,
    float* __restrict__ AB)
{
    __shared__ float W2[16 * 48];   // [j][48]: cols 0..15 w2[0], 16..31 w2[1], 32..47 root2
    __shared__ float hl[16][17];
    for (int t = threadIdx.x; t < 16 * 48; t += 256) {
        int j = t / 48, o = t % 48;
        float v;
        if (o < 16)       v = w2[j * 16 + o];
        else if (o < 32)  v = w2[256 + j * 16 + (o - 16)];
        else              v = root2[j * 16 + (o - 32)];
        W2[t] = v;
    }
    int nl = threadIdx.x >> 4;
    int o  = threadIdx.x & 15;
    int n  = blockIdx.x * 16 + nl;

    float dv  = fmaxf(deg[n], 1.0f);
    float pre = agg[(size_t)n * 16 + o] / dv + C[(size_t)n * 16 + o];
    float h   = pre > 0.f ? pre : expm1f(pre);   // ELU alpha=1
    __syncthreads();          // W2 ready
    hl[nl][o] = h;
    __syncthreads();

    float a = 0.f, b = 0.f, p = 0.f;
#pragma unroll
    for (int j = 0; j < 16; ++j) {
        float hv = hl[nl][j];
        a += hv * W2[j * 48 + o];
        b += hv * W2[j * 48 + 16 + o];
        p += hv * W2[j * 48 + 32 + o];
    }
    AB[(size_t)n * 32 + o]      = a;
    AB[(size_t)n * 32 + 16 + o] = b;
    C[(size_t)n * 16 + o]       = p + b2[o];
}

// ---------------------------------------------------------------------------
// K5: out = log_softmax(agg2/deg + p2) over 16 classes, shuffle-reduce
// within 16-lane groups.
// ---------------------------------------------------------------------------
__global__ __launch_bounds__(256) void k_final(
    const float* __restrict__ agg, const float* __restrict__ deg,
    const float* __restrict__ C, float* __restrict__ out)
{
    int t = blockIdx.x * 256 + threadIdx.x;
    int n = t >> 4;
    int o = t & 15;
    float dv = fmaxf(deg[n], 1.0f);
    float v  = agg[(size_t)n * 16 + o] / dv + C[(size_t)n * 16 + o];
    float m = v;
#pragma unroll
    for (int s = 1; s < 16; s <<= 1) m = fmaxf(m, __shfl_xor(m, s, 16));
    float ex = __expf(v - m);
    float ssum = ex;
#pragma unroll
    for (int s = 1; s < 16; s <<= 1) ssum += __shfl_xor(ssum, s, 16);
    out[(size_t)n * 16 + o] = v - m - __logf(ssum);
}

extern "C" void kernel_launch(void* const* d_in, const int* in_sizes, int n_in,
                              void* d_out, int out_size, void* d_ws, size_t ws_size,
                              hipStream_t stream) {
    const float* x     = (const float*)d_in[0];
    const int*   ei    = (const int*)d_in[1];
    const float* ea    = (const float*)d_in[2];
    const float* w1    = (const float*)d_in[3];
    const float* root1 = (const float*)d_in[4];
    const float* b1    = (const float*)d_in[5];
    const float* w2    = (const float*)d_in[6];
    const float* root2 = (const float*)d_in[7];
    const float* b2    = (const float*)d_in[8];
    float* out = (float*)d_out;

    float* ws  = (float*)d_ws;
    float* AB  = ws;                         // N*32: h0|h1 interleaved
    float* C   = AB + (size_t)N_NODES * 32;  // N*16: p (root path + bias)
    float* AGG = C  + (size_t)N_NODES * 16;  // N*16: scatter accumulator
    float* DEG = AGG + (size_t)N_NODES * 16; // N: degree

    const int* srcp = ei;
    const int* dstp = ei + N_EDGES;

    hipMemsetAsync(AGG, 0, (size_t)N_NODES * 16 * sizeof(float), stream);
    hipMemsetAsync(DEG, 0, (size_t)N_NODES * sizeof(float), stream);

    k_node1<<<N_NODES / 16, 256, 0, stream>>>(x, w1, root1, b1, AB, C);
    k_edge<true><<<(N_EDGES * 16) / 256, 256, 0, stream>>>(srcp, dstp, ea, AB, AGG, DEG);
    k_node2<<<N_NODES / 16, 256, 0, stream>>>(AGG, DEG, C, w2, root2, b2, AB);
    hipMemsetAsync(AGG, 0, (size_t)N_NODES * 16 * sizeof(float), stream);
    k_edge<false><<<(N_EDGES * 16) / 256, 256, 0, stream>>>(srcp, dstp, ea, AB, AGG, nullptr);
    k_final<<<N_NODES / 16, 256, 0, stream>>>(AGG, DEG, C, out);
}